// Round 3
// baseline (113.003 us; speedup 1.0000x reference)
//
#include <hip/hip_runtime.h>
#include <math.h>

// tanh(delta^T M delta) for pairs of 20 amino-acid feature rows.
// idx in [0,20) => only 400 distinct outputs. Each block redundantly builds
// the 400-entry table in LDS (cheap: ~544 FMA/thread, F/M are L2-resident),
// then does a block-chunked 4-deep-unrolled vec4 gather with nontemporal
// stores. Single kernel => no serial 1-block table launch in the graph.

constexpr int NUM_AA = 20;
constexpr int FEAT   = 16;
constexpr int TABLE  = NUM_AA * NUM_AA; // 400

// Native clang vectors — required by __builtin_nontemporal_store (the HIP
// float4/int4 classes are rejected).
typedef float fv4 __attribute__((ext_vector_type(4)));
typedef int   iv4 __attribute__((ext_vector_type(4)));

__global__ __launch_bounds__(256) void snack_fused(
    const float* __restrict__ F,        // [20,16]
    const float* __restrict__ M,        // [16,16]
    const iv4* __restrict__ ii4,        // idx_i as int4
    const iv4* __restrict__ jj4,        // idx_j as int4
    fv4* __restrict__ out4,             // output as float4
    int nvec,                           // P/4
    const int* __restrict__ ii_s,       // scalar views for tail
    const int* __restrict__ jj_s,
    float* __restrict__ out_s,
    int tail_start, int total)          // tail handling (P % 4)
{
    __shared__ float s[TABLE];          // 1.6 KB
    __shared__ float sF[NUM_AA * FEAT]; // 320 floats
    __shared__ float sM[FEAT * FEAT];   // 256 floats

    const int t = threadIdx.x;

    // ---- stage F, M ----
    for (int k = t; k < NUM_AA * FEAT; k += 256) sF[k] = F[k];
    if (t < FEAT * FEAT) sM[t] = M[t];
    __syncthreads();

    // ---- build table: thread t does entries t and t+256 ----
#pragma unroll
    for (int pass = 0; pass < 2; ++pass) {
        const int e = t + pass * 256;
        if (e < TABLE) {
            const int i = e / NUM_AA;
            const int j = e - i * NUM_AA;
            float delta[FEAT];
#pragma unroll
            for (int d = 0; d < FEAT; ++d)
                delta[d] = sF[i * FEAT + d] - sF[j * FEAT + d];
            float dist = 0.f;
#pragma unroll
            for (int d = 0; d < FEAT; ++d) {
                float md = 0.f;
#pragma unroll
                for (int e2 = 0; e2 < FEAT; ++e2)
                    md = fmaf(sM[d * FEAT + e2], delta[e2], md);
                dist = fmaf(delta[d], md, dist);
            }
            s[e] = tanhf(dist);
        }
    }
    __syncthreads();

    // ---- block-chunked gather: each block owns contiguous 1024-vec4 chunks,
    //      4-deep unroll => 8 independent 16B index loads in flight ----
    constexpr int CH = 4 * 256; // vec4 per chunk
    const int stride = (int)gridDim.x * CH;

    for (int base = blockIdx.x * CH; base < nvec; base += stride) {
        const int v0 = base + t;
        if (base + CH <= nvec) {
            const iv4 iA = ii4[v0];
            const iv4 jA = jj4[v0];
            const iv4 iB = ii4[v0 + 256];
            const iv4 jB = jj4[v0 + 256];
            const iv4 iC = ii4[v0 + 512];
            const iv4 jC = jj4[v0 + 512];
            const iv4 iD = ii4[v0 + 768];
            const iv4 jD = jj4[v0 + 768];
            fv4 oA, oB, oC, oD;
            oA.x = s[iA.x * NUM_AA + jA.x];
            oA.y = s[iA.y * NUM_AA + jA.y];
            oA.z = s[iA.z * NUM_AA + jA.z];
            oA.w = s[iA.w * NUM_AA + jA.w];
            oB.x = s[iB.x * NUM_AA + jB.x];
            oB.y = s[iB.y * NUM_AA + jB.y];
            oB.z = s[iB.z * NUM_AA + jB.z];
            oB.w = s[iB.w * NUM_AA + jB.w];
            oC.x = s[iC.x * NUM_AA + jC.x];
            oC.y = s[iC.y * NUM_AA + jC.y];
            oC.z = s[iC.z * NUM_AA + jC.z];
            oC.w = s[iC.w * NUM_AA + jC.w];
            oD.x = s[iD.x * NUM_AA + jD.x];
            oD.y = s[iD.y * NUM_AA + jD.y];
            oD.z = s[iD.z * NUM_AA + jD.z];
            oD.w = s[iD.w * NUM_AA + jD.w];
            __builtin_nontemporal_store(oA, &out4[v0]);
            __builtin_nontemporal_store(oB, &out4[v0 + 256]);
            __builtin_nontemporal_store(oC, &out4[v0 + 512]);
            __builtin_nontemporal_store(oD, &out4[v0 + 768]);
        } else {
            for (int v = v0; v < nvec; v += 256) {
                const iv4 iA = ii4[v];
                const iv4 jA = jj4[v];
                fv4 oA;
                oA.x = s[iA.x * NUM_AA + jA.x];
                oA.y = s[iA.y * NUM_AA + jA.y];
                oA.z = s[iA.z * NUM_AA + jA.z];
                oA.w = s[iA.w * NUM_AA + jA.w];
                __builtin_nontemporal_store(oA, &out4[v]);
            }
        }
    }

    // tail (P % 4 != 0) — block 0 handles up to 3 scalars
    if (blockIdx.x == 0) {
        const int p = tail_start + t;
        if (p < total)
            out_s[p] = s[ii_s[p] * NUM_AA + jj_s[p]];
    }
}

extern "C" void kernel_launch(void* const* d_in, const int* in_sizes, int n_in,
                              void* d_out, int out_size, void* d_ws, size_t ws_size,
                              hipStream_t stream)
{
    const float* F   = (const float*)d_in[0];
    const float* M   = (const float*)d_in[1];
    const int*   ii  = (const int*)d_in[2];
    const int*   jj  = (const int*)d_in[3];
    float*       out = (float*)d_out;

    const int P    = in_sizes[2];
    const int nvec = P >> 2;           // 2,097,152 for P = 8,388,608
    const int tail = nvec << 2;        // first scalar index of tail (== P here)

    // Each block consumes chunks of 1024 vec4. 2048 blocks = 8/CU.
    int blocks = (nvec + 1023) / 1024;
    if (blocks > 2048) blocks = 2048;
    if (blocks < 1)    blocks = 1;

    snack_fused<<<blocks, 256, 0, stream>>>(
        F, M, (const iv4*)ii, (const iv4*)jj, (fv4*)out,
        nvec, ii, jj, out, tail, P);
}